// Round 17
// baseline (398.161 us; speedup 1.0000x reference)
//
#include <hip/hip_runtime.h>
#include <math.h>

// ---------------- problem constants ----------------
#define NN    36864        // N = B*V
#define F0    1025
#define H1D   256
#define H2D   64
#define VV    36
#define SS    12
#define BSZ   1024         // N / V
#define BN_EPS 1e-5f

#define KT1   17                       // ceil(1025/64)
#define EMB_LD 1088                    // padded embedding row (17*64)
#define WT1_STRIDE  ((size_t)4*17*8192)     // bf16 elems per branch (W1 tiles)
#define WT2_STRIDE  ((size_t)4*8192)

typedef __bf16 bf16x8 __attribute__((ext_vector_type(8)));
typedef __bf16 bf16x4 __attribute__((ext_vector_type(4)));
typedef float  f32x4  __attribute__((ext_vector_type(4)));

__device__ __forceinline__ float4 ld4u(const float* p) {
    float4 v;
    __builtin_memcpy(&v, p, 16);
    return v;
}

__device__ __forceinline__ float dinv_f(float d) {
    return d > 0.f ? rsqrtf(fmaxf(d, 1.f)) : 0.f;
}

// ---------------- fused graph prep (+ stats zeroing): deg + Adj per (block, branch) ----
__global__ __launch_bounds__(128) void k_graph(
    const int* __restrict__ eiF, const int* __restrict__ eiD,
    int E, float* __restrict__ AdjAll, float* __restrict__ stAll) {
    __shared__ float deg_s[VV];
    __shared__ float Adj_s[VV * VV];
    int b = blockIdx.x, br = blockIdx.y, t = threadIdx.x;
    const int* e0 = br ? eiD : eiF;      // row0; row1 at e0 + E
    const int Eh = E / 2;
    const int base = b * VV;

    if (b == 0 && br == 0)               // zero st1+st2 (1280 floats) once per call
        for (int i = t; i < 2 * (2 * H1D + 2 * H2D); i += 128) stAll[i] = 0.f;

    if (t < VV) deg_s[t] = 8.f;
    for (int i = t; i < VV * VV; i += 128) Adj_s[i] = 0.f;
    __syncthreads();

    for (int i = t; i < 288; i += 128) {
        int d = e0[Eh + b * 288 + i];
        atomicAdd(&deg_s[d - base], 1.f);
    }
    __syncthreads();

    for (int i = t; i < 576; i += 128) {
        int idx = (i < 288) ? (b * 288 + i) : (Eh + b * 288 + (i - 288));
        int s = e0[idx], d = e0[E + idx];
        float w = -dinv_f(deg_s[s - base]) * dinv_f(deg_s[d - base]);
        atomicAdd(&Adj_s[(d - base) * VV + (s - base)], w);
    }
    __syncthreads();

    float* A = AdjAll + ((size_t)br * BSZ + b) * (VV * VV);
    for (int i = t; i < VV * VV; i += 128) A[i] = Adj_s[i];
}

// ---------------- prep EmbSum ----------------
__global__ __launch_bounds__(256) void k_prepEmb(
    const float* __restrict__ TembF, const float* __restrict__ SembF,
    const float* __restrict__ TembD, const float* __restrict__ SembD,
    float* __restrict__ embSAll) {
    int br = blockIdx.y;
    const float* Temb = br ? TembD : TembF;
    const float* Semb = br ? SembD : SembF;
    float* out = embSAll + (size_t)br * VV * EMB_LD;
    int id = blockIdx.x * 256 + threadIdx.x;
    if (id >= VV * (EMB_LD / 4)) return;
    int lv = id / (EMB_LD / 4);
    int k0 = (id - lv * (EMB_LD / 4)) * 4;
    const float* pt = Temb + (size_t)(lv / SS) * F0;
    const float* ps = Semb + (size_t)(lv % SS) * F0;
    float4 v;
    float* vp = (float*)&v;
#pragma unroll
    for (int j = 0; j < 4; ++j) {
        int k = k0 + j;
        vp[j] = (k < F0) ? (pt[k] + ps[k]) : 0.f;
    }
    *reinterpret_cast<float4*>(out + (size_t)lv * EMB_LD + k0) = v;
}

// ---------------- prep W: [bn][kt][128c x 64k] tiled+swizzled ----------------
__global__ __launch_bounds__(256) void k_prepW(
    const float* __restrict__ WaF, const float* __restrict__ WbF,
    const float* __restrict__ WaD, const float* __restrict__ WbD,
    __bf16* __restrict__ Wt, int K, int nkt, int split, int ldw, size_t brStride) {
    int br = blockIdx.y;
    const float* Wa = br ? WaD : WaF;
    const float* Wb = br ? WbD : WbF;
    __bf16* out = Wt + (size_t)br * brStride;

    int id = blockIdx.x * 256 + threadIdx.x;
    int gpc = nkt * 8;
    int c = id / gpc, gi = id - c * gpc;
    int kt = gi >> 3, g = gi & 7;
    int k0 = kt * 64 + g * 8;
    const float* src = (c < split) ? (Wa + c) : (Wb + (c - split));
    bf16x8 ov;
#pragma unroll
    for (int j = 0; j < 8; ++j) {
        int k = k0 + j;
        float v = (k < K) ? src[(size_t)k * ldw] : 0.f;
        ov[j] = (__bf16)v;
    }
    int r = c & 127, bn = c >> 7;
    size_t dst = ((size_t)(bn * nkt + kt) << 13) + r * 64 + ((g ^ (r & 7)) << 3);
    *(bf16x8*)(out + dst) = ov;
}

// ---------------- fused GEMM1: H = (x+embS) @ [W0|W1], bf16 out ----------------
// 128x256 tile, 8 waves, 96 KB LDS dbuf, XCD-swizzled 1152 grid (R11 geometry).
// NEW (T4): steady K-loop uses raw s_barrier + counted "s_waitcnt vmcnt(8)" so the
// depth-2 x/embS register prefetch AND the next-tile B DMA survive phase boundaries
// (__syncthreads' vmcnt(0) was draining them). Invariant: 12 vmem ops in flight
// (B(j):4 oldest, X(j+1):4, E(j+1):4); wait drains only B(j). Tiles 14-16 use the
// proven __syncthreads tail (boundary-branchy issueX). launch_bounds(512,2) grants
// 256 VGPR/wave so the +32-reg embS slots don't spill (R10/R15 lesson).
__global__ __launch_bounds__(512, 2) void k_gemm1f(
    const float* __restrict__ xF, const float* __restrict__ xD,
    const float* __restrict__ embSAll,
    const __bf16* __restrict__ Wt1All,
    __bf16* __restrict__ H0All, __bf16* __restrict__ H1All) {
    __shared__ __align__(16) __bf16 As[2 * 8192];    // 32 KB
    __shared__ __align__(16) __bf16 Bs[2 * 16384];   // 64 KB
    const int tid = threadIdx.x;
    const int lane = tid & 63, wid = tid >> 6;

    const int flat = blockIdx.x;
    const int w = (flat & 7) * 144 + (flat >> 3);
    const int cy = w & 1;
    const int t2 = w >> 1;            // 0..575
    const int bm = t2 % 288;
    const int br = t2 / 288;

    const float* x    = br ? xD : xF;
    const float* embS = embSAll + (size_t)br * VV * EMB_LD;
    const __bf16* Wt = Wt1All + (size_t)br * WT1_STRIDE;
    __bf16* H0 = H0All + (size_t)br * NN * H1D;
    __bf16* H1 = H1All + (size_t)br * NN * H1D;

    const int wr = wid >> 2, wc = wid & 3;
    const int l15 = lane & 15, lg = lane >> 4;
    const int bn0 = cy * 2;

    const int kc = (lane & 15) * 4;
    const float *px[4], *pe[4];
    int dso[4];
#pragma unroll
    for (int i = 0; i < 4; ++i) {
        int r = wid * 16 + i * 4 + (lane >> 4);
        int g = bm * 128 + r;
        int lv = g % VV;
        px[i] = x + (size_t)g * F0 + kc;
        pe[i] = embS + (size_t)lv * EMB_LD + kc;
        dso[i] = r * 64 + (((kc >> 3) ^ (r & 7)) << 3) + (kc & 4);
    }

    int offA[2][4], offB[2][4];
#pragma unroll
    for (int kk = 0; kk < 2; ++kk) {
#pragma unroll
        for (int m = 0; m < 4; ++m) {
            int rowA = wr * 64 + m * 16 + l15;
            offA[kk][m] = rowA * 64 + (((kk * 4 + lg) ^ (rowA & 7)) << 3);
        }
#pragma unroll
        for (int n = 0; n < 4; ++n) {
            int col = wc * 64 + n * 16 + l15;      // 0..255
            offB[kk][n] = (col >> 7) * 8192 + (col & 127) * 64
                          + (((kk * 4 + lg) ^ (col & 7)) << 3);
        }
    }

    f32x4 acc[4][4];
#pragma unroll
    for (int m = 0; m < 4; ++m)
#pragma unroll
        for (int n = 0; n < 4; ++n) acc[m][n] = (f32x4){0.f, 0.f, 0.f, 0.f};

    f32x4 xa0[4], xa1[4];      // depth-2 x prefetch slots
    float4 ea0[4], ea1[4];     // depth-2 embS prefetch slots

    auto issueX = [&](int kt, f32x4 (&xa)[4]) {
        int ko = kt * 64, kb = ko + kc;
#pragma unroll
        for (int i = 0; i < 4; ++i) {
            if (kb + 3 < F0) {
                float4 a = ld4u(px[i] + ko);
                xa[i] = (f32x4){a.x, a.y, a.z, a.w};
            } else {
                f32x4 v = {0.f, 0.f, 0.f, 0.f};
#pragma unroll
                for (int j = 0; j < 4; ++j)
                    if (kb + j < F0) v[j] = px[i][ko + j];
                xa[i] = v;
            }
        }
    };
    auto issueE = [&](int kt, float4 (&ea)[4]) {
        int ko = kt * 64;
#pragma unroll
        for (int i = 0; i < 4; ++i)
            ea[i] = *reinterpret_cast<const float4*>(pe[i] + ko);
    };
    auto writeA = [&](int buf, f32x4 (&xa)[4], float4 (&ea)[4]) {
#pragma unroll
        for (int i = 0; i < 4; ++i) {
            bf16x4 wv;
            wv[0] = (__bf16)(xa[i][0] + ea[i].x);
            wv[1] = (__bf16)(xa[i][1] + ea[i].y);
            wv[2] = (__bf16)(xa[i][2] + ea[i].z);
            wv[3] = (__bf16)(xa[i][3] + ea[i].w);
            *(bf16x4*)(As + buf * 8192 + dso[i]) = wv;
        }
    };
    auto issueB = [&](int kt, int buf) {
#pragma unroll
        for (int cc = 0; cc < 4; ++cc) {
            int q = (wid * 4 + cc) * 512;
            int h = q >> 13, qi = q & 8191;        // wave-uniform
            const __bf16* src = Wt + (((size_t)(bn0 + h) * KT1 + kt) << 13)
                                + qi + (lane << 3);
            __builtin_amdgcn_global_load_lds(
                (const __attribute__((address_space(1))) void*)src,
                (__attribute__((address_space(3))) void*)(Bs + buf * 16384 + q), 16, 0, 0);
        }
    };
    auto mfmaStep = [&](int cur) {
        const __bf16* Ab = As + cur * 8192;
        const __bf16* Bb = Bs + cur * 16384;
#pragma unroll
        for (int kk = 0; kk < 2; ++kk) {
            bf16x8 af[4], bb[4];
#pragma unroll
            for (int m = 0; m < 4; ++m) af[m] = *(const bf16x8*)(Ab + offA[kk][m]);
#pragma unroll
            for (int n = 0; n < 4; ++n) bb[n] = *(const bf16x8*)(Bb + offB[kk][n]);
#pragma unroll
            for (int m = 0; m < 4; ++m)
#pragma unroll
                for (int n = 0; n < 4; ++n)
                    acc[m][n] = __builtin_amdgcn_mfma_f32_16x16x32_bf16(
                        af[m], bb[n], acc[m][n], 0, 0, 0);
        }
    };

    // prologue: tile0 A staged from regs (auto-drained), B(0) + X/E(1) in flight
    issueX(0, xa0); issueE(0, ea0);
    writeA(0, xa0, ea0);
    issueB(0, 0);
    issueX(1, xa1); issueE(1, ea1);

    // steady loop: tiles 0..13 (branchless issueX range), counted-vmcnt barriers
    for (int kt = 0; kt + 3 <= 15; kt += 2) {       // kt = 0,2,...,12
        // ---- step A: tile kt (buf0) ----
        asm volatile("s_waitcnt vmcnt(8) lgkmcnt(0)" ::: "memory");
        __builtin_amdgcn_sched_barrier(0);
        __builtin_amdgcn_s_barrier();
        __builtin_amdgcn_sched_barrier(0);
        issueB(kt + 1, 1);
        issueX(kt + 2, xa0); issueE(kt + 2, ea0);
        mfmaStep(0);
        writeA(1, xa1, ea1);                        // tile kt+1 -> buf1
        // ---- step B: tile kt+1 (buf1) ----
        asm volatile("s_waitcnt vmcnt(8) lgkmcnt(0)" ::: "memory");
        __builtin_amdgcn_sched_barrier(0);
        __builtin_amdgcn_s_barrier();
        __builtin_amdgcn_sched_barrier(0);
        issueB(kt + 2, 0);
        issueX(kt + 3, xa1); issueE(kt + 3, ea1);
        mfmaStep(1);
        writeA(0, xa0, ea0);                        // tile kt+2 -> buf0
    }

    // tail: tiles 14, 15, 16 (safe __syncthreads; issueX(16) is boundary-branchy)
    __syncthreads();
    issueB(15, 1);
    issueX(16, xa0); issueE(16, ea0);
    mfmaStep(0);                                    // tile 14
    writeA(1, xa1, ea1);                            // tile 15 -> buf1
    __syncthreads();
    issueB(16, 0);
    mfmaStep(1);                                    // tile 15
    writeA(0, xa0, ea0);                            // tile 16 -> buf0
    __syncthreads();
    mfmaStep(0);                                    // tile 16

    const int cr = lg * 4;
#pragma unroll
    for (int m = 0; m < 4; ++m) {
        int grow = bm * 128 + wr * 64 + m * 16 + cr;
#pragma unroll
        for (int n = 0; n < 4; ++n) {
            int gc = cy * 256 + wc * 64 + n * 16 + l15;
#pragma unroll
            for (int j = 0; j < 4; ++j) {
                int r = grow + j;
                if (gc < 256) H0[(size_t)r * H1D + gc] = (__bf16)acc[m][n][j];
                else          H1[(size_t)r * H1D + (gc - 256)] = (__bf16)acc[m][n][j];
            }
        }
    }
}

// ---------------- fused GEMM2: coef1 computed inline; G = relu(Y*sA+sB) @ [W0b|W1b] ------
__global__ __launch_bounds__(256, 2) void k_gemm2f(
    const __bf16* __restrict__ YAll, const float* __restrict__ stAll,
    const float* __restrict__ gF, const float* __restrict__ btF,
    const float* __restrict__ gD, const float* __restrict__ btD,
    const __bf16* __restrict__ Wt2All,
    float* __restrict__ G0All, __bf16* __restrict__ G1All) {
    __shared__ __align__(16) __bf16 As[2 * 8192];
    __shared__ __align__(16) __bf16 Bs[2 * 8192];
    __shared__ float coef_s[2 * H1D];
    const int tid = threadIdx.x;
    const int lane = tid & 63, wid = tid >> 6;
    const int bm = blockIdx.x, br = blockIdx.z;
    const __bf16* Y   = YAll + (size_t)br * NN * H1D;
    const __bf16* Wt  = Wt2All + (size_t)br * WT2_STRIDE;
    float*  G0 = G0All + (size_t)br * NN * H2D;
    __bf16* G1 = G1All + (size_t)br * NN * H2D;

    {
        const float* st = stAll + (size_t)br * 2 * H1D;
        const float* g  = br ? gD : gF;
        const float* bt = br ? btD : btF;
        int c = tid;
        float mu = st[c] / (float)NN;
        float var = st[H1D + c] / (float)NN - mu * mu;
        float sA = g[c] * rsqrtf(var + BN_EPS);
        coef_s[c] = sA;
        coef_s[H1D + c] = bt[c] - mu * sA;
    }
    __syncthreads();

    const int wr = wid >> 1, wc = wid & 1;
    const int l15 = lane & 15, lg = lane >> 4;

    const int kc = (lane & 15) * 4;
    const __bf16* pyr[8];
    int dso[8];
#pragma unroll
    for (int i = 0; i < 8; ++i) {
        int r = wid * 32 + i * 4 + (lane >> 4);
        pyr[i] = Y + (size_t)(bm * 128 + r) * H1D + kc;
        dso[i] = r * 64 + (((kc >> 3) ^ (r & 7)) << 3) + (kc & 4);
    }

    int offA[2][4], offB[2][4];
#pragma unroll
    for (int kk = 0; kk < 2; ++kk)
#pragma unroll
        for (int m = 0; m < 4; ++m) {
            int rowA = wr * 64 + m * 16 + l15;
            offA[kk][m] = rowA * 64 + (((kk * 4 + lg) ^ (rowA & 7)) << 3);
            int col = wc * 64 + m * 16 + l15;
            offB[kk][m] = col * 64 + (((kk * 4 + lg) ^ (col & 7)) << 3);
        }

    f32x4 acc[4][4];
#pragma unroll
    for (int m = 0; m < 4; ++m)
#pragma unroll
        for (int n = 0; n < 4; ++n) acc[m][n] = (f32x4){0.f, 0.f, 0.f, 0.f};

    bf16x4 ya[8];

    auto issueY = [&](int kt) {
        int k0 = kt * 64;
#pragma unroll
        for (int i = 0; i < 8; ++i)
            ya[i] = *reinterpret_cast<const bf16x4*>(pyr[i] + k0);
    };
    auto writeA = [&](int kt, int buf) {
        int k0 = kt * 64;
        float4 cA = *reinterpret_cast<const float4*>(coef_s + k0 + kc);
        float4 cB = *reinterpret_cast<const float4*>(coef_s + H1D + k0 + kc);
#pragma unroll
        for (int i = 0; i < 8; ++i) {
            bf16x4 wv;
            wv[0] = (__bf16)fmaxf(fmaf((float)ya[i][0], cA.x, cB.x), 0.f);
            wv[1] = (__bf16)fmaxf(fmaf((float)ya[i][1], cA.y, cB.y), 0.f);
            wv[2] = (__bf16)fmaxf(fmaf((float)ya[i][2], cA.z, cB.z), 0.f);
            wv[3] = (__bf16)fmaxf(fmaf((float)ya[i][3], cA.w, cB.w), 0.f);
            *(bf16x4*)(As + buf * 8192 + dso[i]) = wv;
        }
    };
    auto issueB = [&](int kt, int buf) {
#pragma unroll
        for (int cc = 0; cc < 4; ++cc) {
            int q = (wid * 4 + cc) * 512;
            const __bf16* src = Wt + ((size_t)kt << 13) + q + (lane << 3);
            __builtin_amdgcn_global_load_lds(
                (const __attribute__((address_space(1))) void*)src,
                (__attribute__((address_space(3))) void*)(Bs + buf * 8192 + q), 16, 0, 0);
        }
    };

    issueB(0, 0);
    issueY(0);
    writeA(0, 0);

    for (int kt = 0; kt < 4; ++kt) {
        const int cur = kt & 1, nxt = cur ^ 1;
        __syncthreads();
        if (kt + 1 < 4) {
            issueB(kt + 1, nxt);
            issueY(kt + 1);
        }
        const __bf16* Ab = As + cur * 8192;
        const __bf16* Bb = Bs + cur * 8192;
#pragma unroll
        for (int kk = 0; kk < 2; ++kk) {
            bf16x8 af[4], bb[4];
#pragma unroll
            for (int m = 0; m < 4; ++m) af[m] = *(const bf16x8*)(Ab + offA[kk][m]);
#pragma unroll
            for (int n = 0; n < 4; ++n) bb[n] = *(const bf16x8*)(Bb + offB[kk][n]);
#pragma unroll
            for (int m = 0; m < 4; ++m)
#pragma unroll
                for (int n = 0; n < 4; ++n)
                    acc[m][n] = __builtin_amdgcn_mfma_f32_16x16x32_bf16(
                        af[m], bb[n], acc[m][n], 0, 0, 0);
        }
        if (kt + 1 < 4) writeA(kt + 1, nxt);
    }

    const int cr = lg * 4;
#pragma unroll
    for (int m = 0; m < 4; ++m) {
        int grow = bm * 128 + wr * 64 + m * 16 + cr;
#pragma unroll
        for (int n = 0; n < 4; ++n) {
            int col = wc * 64 + n * 16 + l15;
#pragma unroll
            for (int j = 0; j < 4; ++j) {
                int r = grow + j;
                if (col < 64) G0[(size_t)r * H2D + col] = acc[m][n][j];
                else          G1[(size_t)r * H2D + (col - 64)] = (__bf16)acc[m][n][j];
            }
        }
    }
}

// ---------------- combine1 + BN stats (bf16 Y in-place): Y = H0 + Adj@H1 + b ----------------
__global__ __launch_bounds__(256) void k_combine_stats1(
    const float* __restrict__ AdjAll, const __bf16* __restrict__ H1All,
    const float* __restrict__ bF, const float* __restrict__ bD,
    __bf16* __restrict__ YAll, float* __restrict__ stAll) {
    __shared__ float Adj_s[VV * VV];
    __shared__ float red[256 * 9];
    int b = blockIdx.x, br = blockIdx.y, t = threadIdx.x;
    const float* Adj = AdjAll + ((size_t)br * BSZ + b) * (VV * VV);
    const __bf16* h1 = H1All + ((size_t)br * NN + (size_t)b * VV) * H1D;
    __bf16* yb = YAll + ((size_t)br * NN + (size_t)b * VV) * H1D;
    float* st = stAll + (size_t)br * 2 * H1D;
    const float* bias = br ? bD : bF;

    for (int e = t; e < VV * VV; e += 256) Adj_s[e] = Adj[e];
    __syncthreads();

    int c0 = (t & 63) * 4, r0 = t >> 6;
    float4 bv = *reinterpret_cast<const float4*>(bias + c0);
    float acc[9][4];
#pragma unroll
    for (int i = 0; i < 9; ++i) {
        bf16x4 y = *reinterpret_cast<const bf16x4*>(yb + (size_t)(r0 + 4 * i) * H1D + c0);
        acc[i][0] = (float)y[0] + bv.x; acc[i][1] = (float)y[1] + bv.y;
        acc[i][2] = (float)y[2] + bv.z; acc[i][3] = (float)y[3] + bv.w;
    }
#pragma unroll 4
    for (int j = 0; j < VV; ++j) {
        bf16x4 hv = *reinterpret_cast<const bf16x4*>(h1 + (size_t)j * H1D + c0);
        float h0 = (float)hv[0], h1f = (float)hv[1], h2 = (float)hv[2], h3 = (float)hv[3];
#pragma unroll
        for (int i = 0; i < 9; ++i) {
            float a = Adj_s[(r0 + 4 * i) * VV + j];
            acc[i][0] = fmaf(a, h0, acc[i][0]);
            acc[i][1] = fmaf(a, h1f, acc[i][1]);
            acc[i][2] = fmaf(a, h2, acc[i][2]);
            acc[i][3] = fmaf(a, h3, acc[i][3]);
        }
    }
    float s[4] = {0, 0, 0, 0}, s2[4] = {0, 0, 0, 0};
#pragma unroll
    for (int i = 0; i < 9; ++i) {
        bf16x4 wv;
        wv[0] = (__bf16)acc[i][0]; wv[1] = (__bf16)acc[i][1];
        wv[2] = (__bf16)acc[i][2]; wv[3] = (__bf16)acc[i][3];
        *reinterpret_cast<bf16x4*>(yb + (size_t)(r0 + 4 * i) * H1D + c0) = wv;
#pragma unroll
        for (int k = 0; k < 4; ++k) { s[k] += acc[i][k]; s2[k] += acc[i][k] * acc[i][k]; }
    }
#pragma unroll
    for (int k = 0; k < 4; ++k) { red[t * 9 + k] = s[k]; red[t * 9 + 4 + k] = s2[k]; }
    __syncthreads();
    {
        int cg = t >> 2, k = t & 3;
        float ss = 0.f, ss2 = 0.f;
#pragma unroll
        for (int q = 0; q < 4; ++q) {
            ss  += red[(q * 64 + cg) * 9 + k];
            ss2 += red[(q * 64 + cg) * 9 + 4 + k];
        }
        atomicAdd(&st[t], ss);
        atomicAdd(&st[H1D + t], ss2);
    }
}

// ---------------- combine2 + BN stats (G0 fp32) ----------------
__global__ __launch_bounds__(256) void k_combine_stats2(
    const float* __restrict__ AdjAll, const __bf16* __restrict__ G1All,
    const float* __restrict__ bF, const float* __restrict__ bD,
    float* __restrict__ YAll, float* __restrict__ stAll) {
    __shared__ float Adj_s[VV * VV];
    __shared__ float red[256 * 9];
    int b = blockIdx.x, br = blockIdx.y, t = threadIdx.x;
    const float* Adj = AdjAll + ((size_t)br * BSZ + b) * (VV * VV);
    const __bf16* g1 = G1All + ((size_t)br * NN + (size_t)b * VV) * H2D;
    float* yb = YAll + ((size_t)br * NN + (size_t)b * VV) * H2D;
    float* st = stAll + (size_t)br * 2 * H2D;
    const float* bias = br ? bD : bF;

    for (int e = t; e < VV * VV; e += 256) Adj_s[e] = Adj[e];
    __syncthreads();

    int c0 = (t & 15) * 4, r0 = t >> 4;
    int nr = (r0 < 4) ? 3 : 2;
    float4 bv = *reinterpret_cast<const float4*>(bias + c0);
    float acc[3][4];
    for (int i = 0; i < nr; ++i) {
        float4 y = *reinterpret_cast<const float4*>(yb + (size_t)(r0 + 16 * i) * H2D + c0);
        acc[i][0] = y.x + bv.x; acc[i][1] = y.y + bv.y;
        acc[i][2] = y.z + bv.z; acc[i][3] = y.w + bv.w;
    }
#pragma unroll 4
    for (int j = 0; j < VV; ++j) {
        bf16x4 hv = *reinterpret_cast<const bf16x4*>(g1 + (size_t)j * H2D + c0);
        float h0 = (float)hv[0], h1f = (float)hv[1], h2 = (float)hv[2], h3 = (float)hv[3];
        for (int i = 0; i < nr; ++i) {
            float a = Adj_s[(r0 + 16 * i) * VV + j];
            acc[i][0] = fmaf(a, h0, acc[i][0]);
            acc[i][1] = fmaf(a, h1f, acc[i][1]);
            acc[i][2] = fmaf(a, h2, acc[i][2]);
            acc[i][3] = fmaf(a, h3, acc[i][3]);
        }
    }
    float s[4] = {0, 0, 0, 0}, s2[4] = {0, 0, 0, 0};
    for (int i = 0; i < nr; ++i) {
        *reinterpret_cast<float4*>(yb + (size_t)(r0 + 16 * i) * H2D + c0) =
            make_float4(acc[i][0], acc[i][1], acc[i][2], acc[i][3]);
#pragma unroll
        for (int k = 0; k < 4; ++k) { s[k] += acc[i][k]; s2[k] += acc[i][k] * acc[i][k]; }
    }
#pragma unroll
    for (int k = 0; k < 4; ++k) { red[t * 9 + k] = s[k]; red[t * 9 + 4 + k] = s2[k]; }
    __syncthreads();
    if (t < 2 * H2D) {
        int cg = (t & 63) >> 2, k = t & 3, which = t >> 6;
        float ss = 0.f;
#pragma unroll
        for (int q = 0; q < 16; ++q) ss += red[(q * 16 + cg) * 9 + which * 4 + k];
        atomicAdd(&st[(t >> 6) * H2D + (t & 63)], ss);
    }
}

// ---------------- fused pool + heads (coef2 inline): grid BSZ, 128 threads ----------------
__global__ __launch_bounds__(128) void k_poolheads(
    const float* __restrict__ G0All, const float* __restrict__ st2All,
    const float* __restrict__ gF2, const float* __restrict__ btF2,
    const float* __restrict__ gD2, const float* __restrict__ btD2,
    const float* __restrict__ WlinF, const float* __restrict__ blinF,
    const float* __restrict__ WlinD, const float* __restrict__ blinD,
    const float* __restrict__ Wlin, const float* __restrict__ blin,
    float* __restrict__ out) {
    __shared__ float sF[128], sD[128], lg[24];
    int r = blockIdx.x, t = threadIdx.x;

    {
        int br = t >> 6, c = t & 63;
        const float* Y2 = G0All + (size_t)br * NN * H2D;
        const float* st = st2All + (size_t)br * 2 * H2D;
        const float* g  = br ? gD2 : gF2;
        const float* bt = br ? btD2 : btF2;
        float mu = st[c] / (float)NN;
        float var = st[H2D + c] / (float)NN - mu * mu;
        float sA = g[c] * rsqrtf(var + BN_EPS);
        float sB = bt[c] - mu * sA;
        float mx = -1e30f, sm = 0.f;
        const float* yb = Y2 + ((size_t)r * VV + SS) * H2D + c;
#pragma unroll
        for (int i = 0; i < SS; ++i) {
            float v = fmaxf(fmaf(yb[i * H2D], sA, sB), 0.f);
            mx = fmaxf(mx, v);
            sm += v;
        }
        float* feat = br ? sD : sF;
        feat[c] = mx;
        feat[64 + c] = sm * (1.f / 12.f);
    }
    __syncthreads();

    float* fus = out + 10240 + (size_t)r * 256;
    fus[t] = sF[t];
    fus[128 + t] = sD[t];
    if (t < 5) {
        float a = blinF[t];
        for (int k = 0; k < 128; ++k) a += sF[k] * WlinF[k * 5 + t];
        lg[t] = a;
    } else if (t >= 8 && t < 13) {
        int j = t - 8;
        float a = blinD[j];
        for (int k = 0; k < 128; ++k) a += sD[k] * WlinD[k * 5 + j];
        lg[8 + j] = a;
    } else if (t >= 16 && t < 21) {
        int j = t - 16;
        float a = blin[j];
        for (int k = 0; k < 128; ++k) a += sF[k] * Wlin[k * 5 + j];
        for (int k = 0; k < 128; ++k) a += sD[k] * Wlin[(128 + k) * 5 + j];
        lg[16 + j] = a;
    }
    __syncthreads();
    if (t < 15) {
        int grp = t / 5, j = t % 5;
        const float* l = &lg[grp * 8];
        float m = l[0];
#pragma unroll
        for (int k = 1; k < 5; ++k) m = fmaxf(m, l[k]);
        float den = 0.f;
#pragma unroll
        for (int k = 0; k < 5; ++k) den += expf(l[k] - m);
        float v = expf(l[j] - m) / den;
        float* dst = (grp == 0) ? out : (grp == 1 ? out + 5120 : out + 272384);
        dst[r * 5 + j] = v;
    }
}

// ---------------- launch ----------------
extern "C" void kernel_launch(void* const* d_in, const int* in_sizes, int n_in,
                              void* d_out, int out_size, void* d_ws, size_t ws_size,
                              hipStream_t stream) {
    const float* xF    = (const float*)d_in[0];
    const float* xD    = (const float*)d_in[1];
    const int*   eiF   = (const int*)d_in[2];
    const int*   eiD   = (const int*)d_in[3];
    const float* TembF = (const float*)d_in[4];
    const float* SembF = (const float*)d_in[5];
    const float* TembD = (const float*)d_in[6];
    const float* SembD = (const float*)d_in[7];
    const float* W0F1  = (const float*)d_in[8];
    const float* W1F1  = (const float*)d_in[9];
    const float* bF1   = (const float*)d_in[10];
    const float* gF1   = (const float*)d_in[11];
    const float* btF1  = (const float*)d_in[12];
    const float* W0F2  = (const float*)d_in[13];
    const float* W1F2  = (const float*)d_in[14];
    const float* bF2   = (const float*)d_in[15];
    const float* gF2   = (const float*)d_in[16];
    const float* btF2  = (const float*)d_in[17];
    const float* W0D1  = (const float*)d_in[18];
    const float* W1D1  = (const float*)d_in[19];
    const float* bD1   = (const float*)d_in[20];
    const float* gD1   = (const float*)d_in[21];
    const float* btD1  = (const float*)d_in[22];
    const float* W0D2  = (const float*)d_in[23];
    const float* W1D2  = (const float*)d_in[24];
    const float* bD2   = (const float*)d_in[25];
    const float* gD2   = (const float*)d_in[26];
    const float* btD2  = (const float*)d_in[27];
    const float* WlinF = (const float*)d_in[28];
    const float* blinF = (const float*)d_in[29];
    const float* WlinD = (const float*)d_in[30];
    const float* blinD = (const float*)d_in[31];
    const float* Wlin  = (const float*)d_in[32];
    const float* blin  = (const float*)d_in[33];

    const int E = in_sizes[2] / 2;   // 589824 per branch

    // -------- workspace layout (float units); [2] = branch-major --------
    float* ws = (float*)d_ws;
    size_t o = 0;
    __bf16* H0bf = (__bf16*)(ws + o);   o += (size_t)2 * NN * H1D / 2;
    __bf16* H1bf = (__bf16*)(ws + o);   o += (size_t)2 * NN * H1D / 2;
    float*  G0   = ws + o;              o += (size_t)2 * NN * H2D;
    __bf16* G1bf = (__bf16*)(ws + o);   o += (size_t)2 * NN * H2D / 2;
    __bf16* Wt1  = (__bf16*)(ws + o);   o += (size_t)2 * WT1_STRIDE / 2;
    __bf16* Wt2  = (__bf16*)(ws + o);   o += (size_t)2 * WT2_STRIDE / 2;
    float*  embS = ws + o;              o += (size_t)2 * VV * EMB_LD;
    float*  Adj  = ws + o;              o += (size_t)2 * BSZ * VV * VV;
    float*  st1  = ws + o;              o += 2 * 2 * H1D;    // st1 then st2 contiguous
    float*  st2  = ws + o;              o += 2 * 2 * H2D;

    k_graph<<<dim3(BSZ, 2), 128, 0, stream>>>(eiF, eiD, E, Adj, st1);
    k_prepEmb<<<dim3(39, 2), 256, 0, stream>>>(TembF, SembF, TembD, SembD, embS);
    k_prepW<<<dim3(272, 2), 256, 0, stream>>>(W0F1, W1F1, W0D1, W1D1, Wt1,
                                              F0, 17, 256, H1D, WT1_STRIDE);
    k_prepW<<<dim3(16, 2), 256, 0, stream>>>(W0F2, W1F2, W0D2, W1D2, Wt2,
                                             H1D, 4, 64, H2D, WT2_STRIDE);
    k_gemm1f<<<dim3(1152), 512, 0, stream>>>(xF, xD, embS, Wt1, H0bf, H1bf);
    k_combine_stats1<<<dim3(BSZ, 2), 256, 0, stream>>>(Adj, H1bf, bF1, bD1, H0bf, st1);
    k_gemm2f<<<dim3(288, 1, 2), 256, 0, stream>>>(H0bf, st1, gF1, btF1, gD1, btD1,
                                                  Wt2, G0, G1bf);
    k_combine_stats2<<<dim3(BSZ, 2), 256, 0, stream>>>(Adj, G1bf, bF2, bD2, G0, st2);
    k_poolheads<<<dim3(BSZ), 128, 0, stream>>>(G0, st2, gF2, btF2, gD2, btD2,
                                               WlinF, blinF, WlinD, blinD,
                                               Wlin, blin, (float*)d_out);
}

// Round 18
// 395.545 us; speedup vs baseline: 1.0066x; 1.0066x over previous
//
#include <hip/hip_runtime.h>
#include <math.h>

// ---------------- problem constants ----------------
#define NN    36864        // N = B*V
#define F0    1025
#define H1D   256
#define H2D   64
#define VV    36
#define SS    12
#define BSZ   1024         // N / V
#define BN_EPS 1e-5f

#define KT1   17                       // ceil(1025/64)
#define EMB_LD 1088                    // padded embedding row (17*64)
#define WT1_STRIDE  ((size_t)4*17*8192)     // bf16 elems per branch (W1 tiles)
#define WT2_STRIDE  ((size_t)4*8192)

typedef __bf16 bf16x8 __attribute__((ext_vector_type(8)));
typedef __bf16 bf16x4 __attribute__((ext_vector_type(4)));
typedef float  f32x4  __attribute__((ext_vector_type(4)));

__device__ __forceinline__ float4 ld4u(const float* p) {
    float4 v;
    __builtin_memcpy(&v, p, 16);
    return v;
}

__device__ __forceinline__ float dinv_f(float d) {
    return d > 0.f ? rsqrtf(fmaxf(d, 1.f)) : 0.f;
}

// ---------------- fused graph prep (+ stats zeroing): deg + Adj per (block, branch) ----
__global__ __launch_bounds__(128) void k_graph(
    const int* __restrict__ eiF, const int* __restrict__ eiD,
    int E, float* __restrict__ AdjAll, float* __restrict__ stAll) {
    __shared__ float deg_s[VV];
    __shared__ float Adj_s[VV * VV];
    int b = blockIdx.x, br = blockIdx.y, t = threadIdx.x;
    const int* e0 = br ? eiD : eiF;      // row0; row1 at e0 + E
    const int Eh = E / 2;
    const int base = b * VV;

    if (b == 0 && br == 0)               // zero st1+st2 (1280 floats) once per call
        for (int i = t; i < 2 * (2 * H1D + 2 * H2D); i += 128) stAll[i] = 0.f;

    if (t < VV) deg_s[t] = 8.f;
    for (int i = t; i < VV * VV; i += 128) Adj_s[i] = 0.f;
    __syncthreads();

    for (int i = t; i < 288; i += 128) {
        int d = e0[Eh + b * 288 + i];
        atomicAdd(&deg_s[d - base], 1.f);
    }
    __syncthreads();

    for (int i = t; i < 576; i += 128) {
        int idx = (i < 288) ? (b * 288 + i) : (Eh + b * 288 + (i - 288));
        int s = e0[idx], d = e0[E + idx];
        float w = -dinv_f(deg_s[s - base]) * dinv_f(deg_s[d - base]);
        atomicAdd(&Adj_s[(d - base) * VV + (s - base)], w);
    }
    __syncthreads();

    float* A = AdjAll + ((size_t)br * BSZ + b) * (VV * VV);
    for (int i = t; i < VV * VV; i += 128) A[i] = Adj_s[i];
}

// ---------------- prep EmbSum ----------------
__global__ __launch_bounds__(256) void k_prepEmb(
    const float* __restrict__ TembF, const float* __restrict__ SembF,
    const float* __restrict__ TembD, const float* __restrict__ SembD,
    float* __restrict__ embSAll) {
    int br = blockIdx.y;
    const float* Temb = br ? TembD : TembF;
    const float* Semb = br ? SembD : SembF;
    float* out = embSAll + (size_t)br * VV * EMB_LD;
    int id = blockIdx.x * 256 + threadIdx.x;
    if (id >= VV * (EMB_LD / 4)) return;
    int lv = id / (EMB_LD / 4);
    int k0 = (id - lv * (EMB_LD / 4)) * 4;
    const float* pt = Temb + (size_t)(lv / SS) * F0;
    const float* ps = Semb + (size_t)(lv % SS) * F0;
    float4 v;
    float* vp = (float*)&v;
#pragma unroll
    for (int j = 0; j < 4; ++j) {
        int k = k0 + j;
        vp[j] = (k < F0) ? (pt[k] + ps[k]) : 0.f;
    }
    *reinterpret_cast<float4*>(out + (size_t)lv * EMB_LD + k0) = v;
}

// ---------------- prep W: [bn][kt][128c x 64k] tiled+swizzled ----------------
__global__ __launch_bounds__(256) void k_prepW(
    const float* __restrict__ WaF, const float* __restrict__ WbF,
    const float* __restrict__ WaD, const float* __restrict__ WbD,
    __bf16* __restrict__ Wt, int K, int nkt, int split, int ldw, size_t brStride) {
    int br = blockIdx.y;
    const float* Wa = br ? WaD : WaF;
    const float* Wb = br ? WbD : WbF;
    __bf16* out = Wt + (size_t)br * brStride;

    int id = blockIdx.x * 256 + threadIdx.x;
    int gpc = nkt * 8;
    int c = id / gpc, gi = id - c * gpc;
    int kt = gi >> 3, g = gi & 7;
    int k0 = kt * 64 + g * 8;
    const float* src = (c < split) ? (Wa + c) : (Wb + (c - split));
    bf16x8 ov;
#pragma unroll
    for (int j = 0; j < 8; ++j) {
        int k = k0 + j;
        float v = (k < K) ? src[(size_t)k * ldw] : 0.f;
        ov[j] = (__bf16)v;
    }
    int r = c & 127, bn = c >> 7;
    size_t dst = ((size_t)(bn * nkt + kt) << 13) + r * 64 + ((g ^ (r & 7)) << 3);
    *(bf16x8*)(out + dst) = ov;
}

// ---------------- fused GEMM1 (R11/R14/R16 proven): H = (x+embS) @ [W0|W1], bf16 out ------
// FLAT grid 1152 = 8 XCD x 144 slots (bijective swizzle; cy-pair adjacent per XCD).
// 512 threads = 8 waves (2x4), 128x256 tile, 96 KB LDS dbuf, 104 VGPR (no spill).
// Depth-2 consume shift for x (2x 16-reg slots); embS inline (L2-resident).
__global__ __launch_bounds__(512) void k_gemm1f(
    const float* __restrict__ xF, const float* __restrict__ xD,
    const float* __restrict__ embSAll,
    const __bf16* __restrict__ Wt1All,
    __bf16* __restrict__ H0All, __bf16* __restrict__ H1All) {
    __shared__ __align__(16) __bf16 As[2 * 8192];    // 32 KB
    __shared__ __align__(16) __bf16 Bs[2 * 16384];   // 64 KB
    const int tid = threadIdx.x;
    const int lane = tid & 63, wid = tid >> 6;

    const int flat = blockIdx.x;
    const int w = (flat & 7) * 144 + (flat >> 3);
    const int cy = w & 1;
    const int t2 = w >> 1;            // 0..575
    const int bm = t2 % 288;
    const int br = t2 / 288;

    const float* x    = br ? xD : xF;
    const float* embS = embSAll + (size_t)br * VV * EMB_LD;
    const __bf16* Wt = Wt1All + (size_t)br * WT1_STRIDE;
    __bf16* H0 = H0All + (size_t)br * NN * H1D;
    __bf16* H1 = H1All + (size_t)br * NN * H1D;

    const int wr = wid >> 2, wc = wid & 3;
    const int l15 = lane & 15, lg = lane >> 4;
    const int bn0 = cy * 2;

    const int kc = (lane & 15) * 4;
    const float *px[4], *pe[4];
    int dso[4];
#pragma unroll
    for (int i = 0; i < 4; ++i) {
        int r = wid * 16 + i * 4 + (lane >> 4);
        int g = bm * 128 + r;
        int lv = g % VV;
        px[i] = x + (size_t)g * F0 + kc;
        pe[i] = embS + (size_t)lv * EMB_LD + kc;
        dso[i] = r * 64 + (((kc >> 3) ^ (r & 7)) << 3) + (kc & 4);
    }

    int offA[2][4], offB[2][4];
#pragma unroll
    for (int kk = 0; kk < 2; ++kk) {
#pragma unroll
        for (int m = 0; m < 4; ++m) {
            int rowA = wr * 64 + m * 16 + l15;
            offA[kk][m] = rowA * 64 + (((kk * 4 + lg) ^ (rowA & 7)) << 3);
        }
#pragma unroll
        for (int n = 0; n < 4; ++n) {
            int col = wc * 64 + n * 16 + l15;      // 0..255
            offB[kk][n] = (col >> 7) * 8192 + (col & 127) * 64
                          + (((kk * 4 + lg) ^ (col & 7)) << 3);
        }
    }

    f32x4 acc[4][4];
#pragma unroll
    for (int m = 0; m < 4; ++m)
#pragma unroll
        for (int n = 0; n < 4; ++n) acc[m][n] = (f32x4){0.f, 0.f, 0.f, 0.f};

    f32x4 xa0[4], xa1[4];

    auto issueX = [&](int kt, f32x4 (&xa)[4]) {
        int ko = kt * 64, kb = ko + kc;
#pragma unroll
        for (int i = 0; i < 4; ++i) {
            if (kb + 3 < F0) {
                float4 a = ld4u(px[i] + ko);
                xa[i] = (f32x4){a.x, a.y, a.z, a.w};
            } else {
                f32x4 v = {0.f, 0.f, 0.f, 0.f};
#pragma unroll
                for (int j = 0; j < 4; ++j)
                    if (kb + j < F0) v[j] = px[i][ko + j];
                xa[i] = v;
            }
        }
    };
    auto writeA = [&](int kt, int buf, f32x4 (&xa)[4]) {
        int ko = kt * 64;
#pragma unroll
        for (int i = 0; i < 4; ++i) {
            float4 e = *reinterpret_cast<const float4*>(pe[i] + ko);
            bf16x4 wv;
            wv[0] = (__bf16)(xa[i][0] + e.x);
            wv[1] = (__bf16)(xa[i][1] + e.y);
            wv[2] = (__bf16)(xa[i][2] + e.z);
            wv[3] = (__bf16)(xa[i][3] + e.w);
            *(bf16x4*)(As + buf * 8192 + dso[i]) = wv;
        }
    };
    auto issueB = [&](int kt, int buf) {
#pragma unroll
        for (int cc = 0; cc < 4; ++cc) {
            int q = (wid * 4 + cc) * 512;
            int h = q >> 13, qi = q & 8191;        // wave-uniform
            const __bf16* src = Wt + (((size_t)(bn0 + h) * KT1 + kt) << 13)
                                + qi + (lane << 3);
            __builtin_amdgcn_global_load_lds(
                (const __attribute__((address_space(1))) void*)src,
                (__attribute__((address_space(3))) void*)(Bs + buf * 16384 + q), 16, 0, 0);
        }
    };
    auto mfmaStep = [&](int cur) {
        const __bf16* Ab = As + cur * 8192;
        const __bf16* Bb = Bs + cur * 16384;
#pragma unroll
        for (int kk = 0; kk < 2; ++kk) {
            bf16x8 af[4], bb[4];
#pragma unroll
            for (int m = 0; m < 4; ++m) af[m] = *(const bf16x8*)(Ab + offA[kk][m]);
#pragma unroll
            for (int n = 0; n < 4; ++n) bb[n] = *(const bf16x8*)(Bb + offB[kk][n]);
#pragma unroll
            for (int m = 0; m < 4; ++m)
#pragma unroll
                for (int n = 0; n < 4; ++n)
                    acc[m][n] = __builtin_amdgcn_mfma_f32_16x16x32_bf16(
                        af[m], bb[n], acc[m][n], 0, 0, 0);
        }
    };

    issueX(0, xa0);
    issueB(0, 0);
    writeA(0, 0, xa0);
    issueX(1, xa1);

    for (int kt = 0; kt < KT1; kt += 2) {
        __syncthreads();
        if (kt + 1 < KT1) issueB(kt + 1, 1);
        if (kt + 2 < KT1) issueX(kt + 2, xa0);
        mfmaStep(0);
        if (kt + 1 < KT1) writeA(kt + 1, 1, xa1);
        if (kt + 1 >= KT1) break;
        __syncthreads();
        if (kt + 2 < KT1) issueB(kt + 2, 0);
        if (kt + 3 < KT1) issueX(kt + 3, xa1);
        mfmaStep(1);
        if (kt + 2 < KT1) writeA(kt + 2, 0, xa0);
    }

    const int cr = lg * 4;
#pragma unroll
    for (int m = 0; m < 4; ++m) {
        int grow = bm * 128 + wr * 64 + m * 16 + cr;
#pragma unroll
        for (int n = 0; n < 4; ++n) {
            int gc = cy * 256 + wc * 64 + n * 16 + l15;
#pragma unroll
            for (int j = 0; j < 4; ++j) {
                int r = grow + j;
                if (gc < 256) H0[(size_t)r * H1D + gc] = (__bf16)acc[m][n][j];
                else          H1[(size_t)r * H1D + (gc - 256)] = (__bf16)acc[m][n][j];
            }
        }
    }
}

// ---------------- fused GEMM2: coef1 computed inline; G = relu(Y*sA+sB) @ [W0b|W1b] ------
__global__ __launch_bounds__(256, 2) void k_gemm2f(
    const __bf16* __restrict__ YAll, const float* __restrict__ stAll,
    const float* __restrict__ gF, const float* __restrict__ btF,
    const float* __restrict__ gD, const float* __restrict__ btD,
    const __bf16* __restrict__ Wt2All,
    float* __restrict__ G0All, __bf16* __restrict__ G1All) {
    __shared__ __align__(16) __bf16 As[2 * 8192];
    __shared__ __align__(16) __bf16 Bs[2 * 8192];
    __shared__ float coef_s[2 * H1D];
    const int tid = threadIdx.x;
    const int lane = tid & 63, wid = tid >> 6;
    const int bm = blockIdx.x, br = blockIdx.z;
    const __bf16* Y   = YAll + (size_t)br * NN * H1D;
    const __bf16* Wt  = Wt2All + (size_t)br * WT2_STRIDE;
    float*  G0 = G0All + (size_t)br * NN * H2D;
    __bf16* G1 = G1All + (size_t)br * NN * H2D;

    {
        const float* st = stAll + (size_t)br * 2 * H1D;
        const float* g  = br ? gD : gF;
        const float* bt = br ? btD : btF;
        int c = tid;
        float mu = st[c] / (float)NN;
        float var = st[H1D + c] / (float)NN - mu * mu;
        float sA = g[c] * rsqrtf(var + BN_EPS);
        coef_s[c] = sA;
        coef_s[H1D + c] = bt[c] - mu * sA;
    }
    __syncthreads();

    const int wr = wid >> 1, wc = wid & 1;
    const int l15 = lane & 15, lg = lane >> 4;

    const int kc = (lane & 15) * 4;
    const __bf16* pyr[8];
    int dso[8];
#pragma unroll
    for (int i = 0; i < 8; ++i) {
        int r = wid * 32 + i * 4 + (lane >> 4);
        pyr[i] = Y + (size_t)(bm * 128 + r) * H1D + kc;
        dso[i] = r * 64 + (((kc >> 3) ^ (r & 7)) << 3) + (kc & 4);
    }

    int offA[2][4], offB[2][4];
#pragma unroll
    for (int kk = 0; kk < 2; ++kk)
#pragma unroll
        for (int m = 0; m < 4; ++m) {
            int rowA = wr * 64 + m * 16 + l15;
            offA[kk][m] = rowA * 64 + (((kk * 4 + lg) ^ (rowA & 7)) << 3);
            int col = wc * 64 + m * 16 + l15;
            offB[kk][m] = col * 64 + (((kk * 4 + lg) ^ (col & 7)) << 3);
        }

    f32x4 acc[4][4];
#pragma unroll
    for (int m = 0; m < 4; ++m)
#pragma unroll
        for (int n = 0; n < 4; ++n) acc[m][n] = (f32x4){0.f, 0.f, 0.f, 0.f};

    bf16x4 ya[8];

    auto issueY = [&](int kt) {
        int k0 = kt * 64;
#pragma unroll
        for (int i = 0; i < 8; ++i)
            ya[i] = *reinterpret_cast<const bf16x4*>(pyr[i] + k0);
    };
    auto writeA = [&](int kt, int buf) {
        int k0 = kt * 64;
        float4 cA = *reinterpret_cast<const float4*>(coef_s + k0 + kc);
        float4 cB = *reinterpret_cast<const float4*>(coef_s + H1D + k0 + kc);
#pragma unroll
        for (int i = 0; i < 8; ++i) {
            bf16x4 wv;
            wv[0] = (__bf16)fmaxf(fmaf((float)ya[i][0], cA.x, cB.x), 0.f);
            wv[1] = (__bf16)fmaxf(fmaf((float)ya[i][1], cA.y, cB.y), 0.f);
            wv[2] = (__bf16)fmaxf(fmaf((float)ya[i][2], cA.z, cB.z), 0.f);
            wv[3] = (__bf16)fmaxf(fmaf((float)ya[i][3], cA.w, cB.w), 0.f);
            *(bf16x4*)(As + buf * 8192 + dso[i]) = wv;
        }
    };
    auto issueB = [&](int kt, int buf) {
#pragma unroll
        for (int cc = 0; cc < 4; ++cc) {
            int q = (wid * 4 + cc) * 512;
            const __bf16* src = Wt + ((size_t)kt << 13) + q + (lane << 3);
            __builtin_amdgcn_global_load_lds(
                (const __attribute__((address_space(1))) void*)src,
                (__attribute__((address_space(3))) void*)(Bs + buf * 8192 + q), 16, 0, 0);
        }
    };

    issueB(0, 0);
    issueY(0);
    writeA(0, 0);

    for (int kt = 0; kt < 4; ++kt) {
        const int cur = kt & 1, nxt = cur ^ 1;
        __syncthreads();
        if (kt + 1 < 4) {
            issueB(kt + 1, nxt);
            issueY(kt + 1);
        }
        const __bf16* Ab = As + cur * 8192;
        const __bf16* Bb = Bs + cur * 8192;
#pragma unroll
        for (int kk = 0; kk < 2; ++kk) {
            bf16x8 af[4], bb[4];
#pragma unroll
            for (int m = 0; m < 4; ++m) af[m] = *(const bf16x8*)(Ab + offA[kk][m]);
#pragma unroll
            for (int n = 0; n < 4; ++n) bb[n] = *(const bf16x8*)(Bb + offB[kk][n]);
#pragma unroll
            for (int m = 0; m < 4; ++m)
#pragma unroll
                for (int n = 0; n < 4; ++n)
                    acc[m][n] = __builtin_amdgcn_mfma_f32_16x16x32_bf16(
                        af[m], bb[n], acc[m][n], 0, 0, 0);
        }
        if (kt + 1 < 4) writeA(kt + 1, nxt);
    }

    const int cr = lg * 4;
#pragma unroll
    for (int m = 0; m < 4; ++m) {
        int grow = bm * 128 + wr * 64 + m * 16 + cr;
#pragma unroll
        for (int n = 0; n < 4; ++n) {
            int col = wc * 64 + n * 16 + l15;
#pragma unroll
            for (int j = 0; j < 4; ++j) {
                int r = grow + j;
                if (col < 64) G0[(size_t)r * H2D + col] = acc[m][n][j];
                else          G1[(size_t)r * H2D + (col - 64)] = (__bf16)acc[m][n][j];
            }
        }
    }
}

// ---------------- combine1 + BN stats (bf16 Y in-place): Y = H0 + Adj@H1 + b ----------------
__global__ __launch_bounds__(256) void k_combine_stats1(
    const float* __restrict__ AdjAll, const __bf16* __restrict__ H1All,
    const float* __restrict__ bF, const float* __restrict__ bD,
    __bf16* __restrict__ YAll, float* __restrict__ stAll) {
    __shared__ float Adj_s[VV * VV];
    __shared__ float red[256 * 9];
    int b = blockIdx.x, br = blockIdx.y, t = threadIdx.x;
    const float* Adj = AdjAll + ((size_t)br * BSZ + b) * (VV * VV);
    const __bf16* h1 = H1All + ((size_t)br * NN + (size_t)b * VV) * H1D;
    __bf16* yb = YAll + ((size_t)br * NN + (size_t)b * VV) * H1D;
    float* st = stAll + (size_t)br * 2 * H1D;
    const float* bias = br ? bD : bF;

    for (int e = t; e < VV * VV; e += 256) Adj_s[e] = Adj[e];
    __syncthreads();

    int c0 = (t & 63) * 4, r0 = t >> 6;
    float4 bv = *reinterpret_cast<const float4*>(bias + c0);
    float acc[9][4];
#pragma unroll
    for (int i = 0; i < 9; ++i) {
        bf16x4 y = *reinterpret_cast<const bf16x4*>(yb + (size_t)(r0 + 4 * i) * H1D + c0);
        acc[i][0] = (float)y[0] + bv.x; acc[i][1] = (float)y[1] + bv.y;
        acc[i][2] = (float)y[2] + bv.z; acc[i][3] = (float)y[3] + bv.w;
    }
#pragma unroll 4
    for (int j = 0; j < VV; ++j) {
        bf16x4 hv = *reinterpret_cast<const bf16x4*>(h1 + (size_t)j * H1D + c0);
        float h0 = (float)hv[0], h1f = (float)hv[1], h2 = (float)hv[2], h3 = (float)hv[3];
#pragma unroll
        for (int i = 0; i < 9; ++i) {
            float a = Adj_s[(r0 + 4 * i) * VV + j];
            acc[i][0] = fmaf(a, h0, acc[i][0]);
            acc[i][1] = fmaf(a, h1f, acc[i][1]);
            acc[i][2] = fmaf(a, h2, acc[i][2]);
            acc[i][3] = fmaf(a, h3, acc[i][3]);
        }
    }
    float s[4] = {0, 0, 0, 0}, s2[4] = {0, 0, 0, 0};
#pragma unroll
    for (int i = 0; i < 9; ++i) {
        bf16x4 wv;
        wv[0] = (__bf16)acc[i][0]; wv[1] = (__bf16)acc[i][1];
        wv[2] = (__bf16)acc[i][2]; wv[3] = (__bf16)acc[i][3];
        *reinterpret_cast<bf16x4*>(yb + (size_t)(r0 + 4 * i) * H1D + c0) = wv;
#pragma unroll
        for (int k = 0; k < 4; ++k) { s[k] += acc[i][k]; s2[k] += acc[i][k] * acc[i][k]; }
    }
#pragma unroll
    for (int k = 0; k < 4; ++k) { red[t * 9 + k] = s[k]; red[t * 9 + 4 + k] = s2[k]; }
    __syncthreads();
    {
        int cg = t >> 2, k = t & 3;
        float ss = 0.f, ss2 = 0.f;
#pragma unroll
        for (int q = 0; q < 4; ++q) {
            ss  += red[(q * 64 + cg) * 9 + k];
            ss2 += red[(q * 64 + cg) * 9 + 4 + k];
        }
        atomicAdd(&st[t], ss);
        atomicAdd(&st[H1D + t], ss2);
    }
}

// ---------------- combine2 + BN stats (G0 fp32) ----------------
__global__ __launch_bounds__(256) void k_combine_stats2(
    const float* __restrict__ AdjAll, const __bf16* __restrict__ G1All,
    const float* __restrict__ bF, const float* __restrict__ bD,
    float* __restrict__ YAll, float* __restrict__ stAll) {
    __shared__ float Adj_s[VV * VV];
    __shared__ float red[256 * 9];
    int b = blockIdx.x, br = blockIdx.y, t = threadIdx.x;
    const float* Adj = AdjAll + ((size_t)br * BSZ + b) * (VV * VV);
    const __bf16* g1 = G1All + ((size_t)br * NN + (size_t)b * VV) * H2D;
    float* yb = YAll + ((size_t)br * NN + (size_t)b * VV) * H2D;
    float* st = stAll + (size_t)br * 2 * H2D;
    const float* bias = br ? bD : bF;

    for (int e = t; e < VV * VV; e += 256) Adj_s[e] = Adj[e];
    __syncthreads();

    int c0 = (t & 15) * 4, r0 = t >> 4;
    int nr = (r0 < 4) ? 3 : 2;
    float4 bv = *reinterpret_cast<const float4*>(bias + c0);
    float acc[3][4];
    for (int i = 0; i < nr; ++i) {
        float4 y = *reinterpret_cast<const float4*>(yb + (size_t)(r0 + 16 * i) * H2D + c0);
        acc[i][0] = y.x + bv.x; acc[i][1] = y.y + bv.y;
        acc[i][2] = y.z + bv.z; acc[i][3] = y.w + bv.w;
    }
#pragma unroll 4
    for (int j = 0; j < VV; ++j) {
        bf16x4 hv = *reinterpret_cast<const bf16x4*>(g1 + (size_t)j * H2D + c0);
        float h0 = (float)hv[0], h1f = (float)hv[1], h2 = (float)hv[2], h3 = (float)hv[3];
        for (int i = 0; i < nr; ++i) {
            float a = Adj_s[(r0 + 16 * i) * VV + j];
            acc[i][0] = fmaf(a, h0, acc[i][0]);
            acc[i][1] = fmaf(a, h1f, acc[i][1]);
            acc[i][2] = fmaf(a, h2, acc[i][2]);
            acc[i][3] = fmaf(a, h3, acc[i][3]);
        }
    }
    float s[4] = {0, 0, 0, 0}, s2[4] = {0, 0, 0, 0};
    for (int i = 0; i < nr; ++i) {
        *reinterpret_cast<float4*>(yb + (size_t)(r0 + 16 * i) * H2D + c0) =
            make_float4(acc[i][0], acc[i][1], acc[i][2], acc[i][3]);
#pragma unroll
        for (int k = 0; k < 4; ++k) { s[k] += acc[i][k]; s2[k] += acc[i][k] * acc[i][k]; }
    }
#pragma unroll
    for (int k = 0; k < 4; ++k) { red[t * 9 + k] = s[k]; red[t * 9 + 4 + k] = s2[k]; }
    __syncthreads();
    if (t < 2 * H2D) {
        int cg = (t & 63) >> 2, k = t & 3, which = t >> 6;
        float ss = 0.f;
#pragma unroll
        for (int q = 0; q < 16; ++q) ss += red[(q * 16 + cg) * 9 + which * 4 + k];
        atomicAdd(&st[(t >> 6) * H2D + (t & 63)], ss);
    }
}

// ---------------- fused pool + heads (coef2 inline): grid BSZ, 128 threads ----------------
__global__ __launch_bounds__(128) void k_poolheads(
    const float* __restrict__ G0All, const float* __restrict__ st2All,
    const float* __restrict__ gF2, const float* __restrict__ btF2,
    const float* __restrict__ gD2, const float* __restrict__ btD2,
    const float* __restrict__ WlinF, const float* __restrict__ blinF,
    const float* __restrict__ WlinD, const float* __restrict__ blinD,
    const float* __restrict__ Wlin, const float* __restrict__ blin,
    float* __restrict__ out) {
    __shared__ float sF[128], sD[128], lg[24];
    int r = blockIdx.x, t = threadIdx.x;

    {
        int br = t >> 6, c = t & 63;
        const float* Y2 = G0All + (size_t)br * NN * H2D;
        const float* st = st2All + (size_t)br * 2 * H2D;
        const float* g  = br ? gD2 : gF2;
        const float* bt = br ? btD2 : btF2;
        float mu = st[c] / (float)NN;
        float var = st[H2D + c] / (float)NN - mu * mu;
        float sA = g[c] * rsqrtf(var + BN_EPS);
        float sB = bt[c] - mu * sA;
        float mx = -1e30f, sm = 0.f;
        const float* yb = Y2 + ((size_t)r * VV + SS) * H2D + c;
#pragma unroll
        for (int i = 0; i < SS; ++i) {
            float v = fmaxf(fmaf(yb[i * H2D], sA, sB), 0.f);
            mx = fmaxf(mx, v);
            sm += v;
        }
        float* feat = br ? sD : sF;
        feat[c] = mx;
        feat[64 + c] = sm * (1.f / 12.f);
    }
    __syncthreads();

    float* fus = out + 10240 + (size_t)r * 256;
    fus[t] = sF[t];
    fus[128 + t] = sD[t];
    if (t < 5) {
        float a = blinF[t];
        for (int k = 0; k < 128; ++k) a += sF[k] * WlinF[k * 5 + t];
        lg[t] = a;
    } else if (t >= 8 && t < 13) {
        int j = t - 8;
        float a = blinD[j];
        for (int k = 0; k < 128; ++k) a += sD[k] * WlinD[k * 5 + j];
        lg[8 + j] = a;
    } else if (t >= 16 && t < 21) {
        int j = t - 16;
        float a = blin[j];
        for (int k = 0; k < 128; ++k) a += sF[k] * Wlin[k * 5 + j];
        for (int k = 0; k < 128; ++k) a += sD[k] * Wlin[(128 + k) * 5 + j];
        lg[16 + j] = a;
    }
    __syncthreads();
    if (t < 15) {
        int grp = t / 5, j = t % 5;
        const float* l = &lg[grp * 8];
        float m = l[0];
#pragma unroll
        for (int k = 1; k < 5; ++k) m = fmaxf(m, l[k]);
        float den = 0.f;
#pragma unroll
        for (int k = 0; k < 5; ++k) den += expf(l[k] - m);
        float v = expf(l[j] - m) / den;
        float* dst = (grp == 0) ? out : (grp == 1 ? out + 5120 : out + 272384);
        dst[r * 5 + j] = v;
    }
}

// ---------------- launch ----------------
extern "C" void kernel_launch(void* const* d_in, const int* in_sizes, int n_in,
                              void* d_out, int out_size, void* d_ws, size_t ws_size,
                              hipStream_t stream) {
    const float* xF    = (const float*)d_in[0];
    const float* xD    = (const float*)d_in[1];
    const int*   eiF   = (const int*)d_in[2];
    const int*   eiD   = (const int*)d_in[3];
    const float* TembF = (const float*)d_in[4];
    const float* SembF = (const float*)d_in[5];
    const float* TembD = (const float*)d_in[6];
    const float* SembD = (const float*)d_in[7];
    const float* W0F1  = (const float*)d_in[8];
    const float* W1F1  = (const float*)d_in[9];
    const float* bF1   = (const float*)d_in[10];
    const float* gF1   = (const float*)d_in[11];
    const float* btF1  = (const float*)d_in[12];
    const float* W0F2  = (const float*)d_in[13];
    const float* W1F2  = (const float*)d_in[14];
    const float* bF2   = (const float*)d_in[15];
    const float* gF2   = (const float*)d_in[16];
    const float* btF2  = (const float*)d_in[17];
    const float* W0D1  = (const float*)d_in[18];
    const float* W1D1  = (const float*)d_in[19];
    const float* bD1   = (const float*)d_in[20];
    const float* gD1   = (const float*)d_in[21];
    const float* btD1  = (const float*)d_in[22];
    const float* W0D2  = (const float*)d_in[23];
    const float* W1D2  = (const float*)d_in[24];
    const float* bD2   = (const float*)d_in[25];
    const float* gD2   = (const float*)d_in[26];
    const float* btD2  = (const float*)d_in[27];
    const float* WlinF = (const float*)d_in[28];
    const float* blinF = (const float*)d_in[29];
    const float* WlinD = (const float*)d_in[30];
    const float* blinD = (const float*)d_in[31];
    const float* Wlin  = (const float*)d_in[32];
    const float* blin  = (const float*)d_in[33];

    const int E = in_sizes[2] / 2;   // 589824 per branch

    // -------- workspace layout (float units); [2] = branch-major --------
    float* ws = (float*)d_ws;
    size_t o = 0;
    __bf16* H0bf = (__bf16*)(ws + o);   o += (size_t)2 * NN * H1D / 2;
    __bf16* H1bf = (__bf16*)(ws + o);   o += (size_t)2 * NN * H1D / 2;
    float*  G0   = ws + o;              o += (size_t)2 * NN * H2D;
    __bf16* G1bf = (__bf16*)(ws + o);   o += (size_t)2 * NN * H2D / 2;
    __bf16* Wt1  = (__bf16*)(ws + o);   o += (size_t)2 * WT1_STRIDE / 2;
    __bf16* Wt2  = (__bf16*)(ws + o);   o += (size_t)2 * WT2_STRIDE / 2;
    float*  embS = ws + o;              o += (size_t)2 * VV * EMB_LD;
    float*  Adj  = ws + o;              o += (size_t)2 * BSZ * VV * VV;
    float*  st1  = ws + o;              o += 2 * 2 * H1D;    // st1 then st2 contiguous
    float*  st2  = ws + o;              o += 2 * 2 * H2D;

    k_graph<<<dim3(BSZ, 2), 128, 0, stream>>>(eiF, eiD, E, Adj, st1);
    k_prepEmb<<<dim3(39, 2), 256, 0, stream>>>(TembF, SembF, TembD, SembD, embS);
    k_prepW<<<dim3(272, 2), 256, 0, stream>>>(W0F1, W1F1, W0D1, W1D1, Wt1,
                                              F0, 17, 256, H1D, WT1_STRIDE);
    k_prepW<<<dim3(16, 2), 256, 0, stream>>>(W0F2, W1F2, W0D2, W1D2, Wt2,
                                             H1D, 4, 64, H2D, WT2_STRIDE);
    k_gemm1f<<<dim3(1152), 512, 0, stream>>>(xF, xD, embS, Wt1, H0bf, H1bf);
    k_combine_stats1<<<dim3(BSZ, 2), 256, 0, stream>>>(Adj, H1bf, bF1, bD1, H0bf, st1);
    k_gemm2f<<<dim3(288, 1, 2), 256, 0, stream>>>(H0bf, st1, gF1, btF1, gD1, btD1,
                                                  Wt2, G0, G1bf);
    k_combine_stats2<<<dim3(BSZ, 2), 256, 0, stream>>>(Adj, G1bf, bF2, bD2, G0, st2);
    k_poolheads<<<dim3(BSZ), 128, 0, stream>>>(G0, st2, gF2, btF2, gD2, btD2,
                                               WlinF, blinF, WlinD, blinD,
                                               Wlin, blin, (float*)d_out);
}